// Round 4
// baseline (467.165 us; speedup 1.0000x reference)
//
#include <hip/hip_runtime.h>
#include <hip/hip_bf16.h>
#include <math.h>

#define BB 8
#define FH 8
#define NN 2048
#define TIN 5
#define H1 32
#define H2 64

typedef const void* cvp;
typedef __attribute__((ext_vector_type(8))) short short8;
typedef __attribute__((ext_vector_type(4))) float floatx4;

__device__ __forceinline__ float ldx(cvp p, int i, int bf) {
  if (bf) return __bfloat162float(((const __hip_bfloat16*)p)[i]);
  return ((const float*)p)[i];
}

__device__ __forceinline__ float4 ld4(cvp p, int i, int bf) {
  if (bf) {
    const __hip_bfloat162* q = (const __hip_bfloat162*)p;
    float2 a = __bfloat1622float2(q[(i >> 1)]);
    float2 b = __bfloat1622float2(q[(i >> 1) + 1]);
    return make_float4(a.x, a.y, b.x, b.y);
  }
  return ((const float4*)p)[i >> 2];
}

__device__ __forceinline__ float sigf(float x) {
  return 1.f / (1.f + __expf(-x));
}

// ---------------------------------------------------------------- detector
__global__ void k_detect(const unsigned int* __restrict__ w, int* __restrict__ flag) {
  __shared__ int cnt;
  if (threadIdx.x == 0) cnt = 0;
  __syncthreads();
  int local = 0;
  for (int i = threadIdx.x; i < 1024; i += 256) {
    unsigned e = (w[i] >> 7) & 0xFFu;
    local += (e >= 100u && e <= 150u) ? 1 : 0;
  }
  atomicAdd(&cnt, local);
  __syncthreads();
  if (threadIdx.x == 0) *flag = (cnt > 700) ? 1 : 0;
}

// ---------------------------------------------------------------- LSTM (h1 fused)
// Block = 4 waves / 4 nodes. Wave w owns gate-type w; lane keeps its gate
// row's 96 weights in registers. Per step: compute x = elu(W1 @ hist_t) in
// LDS, then gate matvec via same-address float4 broadcasts.
__global__ __launch_bounds__(256, 2) void k_lstm(
    cvp hist, cvp W1, cvp b1, cvp W_ih, cvp W_hh, cvp b_ih, cvp b_hh,
    float* __restrict__ hs, const int* __restrict__ flagp) {
  __shared__ __align__(16) float xh[4][96];   // per node: x[0..31], h[32..95]
  __shared__ float gbuf[4][256];
  __shared__ float W1s[H1][41];               // bank-padded (stride 41)
  __shared__ float b1s[H1];
  __shared__ float xstage[4][40];
  int bf = *flagp;
  int tid = threadIdx.x;
  int w = tid >> 6, lane = tid & 63;
  int g = (w << 6) + lane;
  int n0 = blockIdx.x << 2;
  int node_w = n0 + w;

  for (int i = tid; i < H1 * 40; i += 256) W1s[i / 40][i % 40] = ldx(W1, i, bf);
  if (tid < H1) b1s[tid] = ldx(b1, tid, bf);

  float wreg[96];
#pragma unroll
  for (int kq = 0; kq < 8; ++kq) {
    float4 v = ld4(W_ih, g * 32 + (kq << 2), bf);
    wreg[(kq << 2) + 0] = v.x; wreg[(kq << 2) + 1] = v.y;
    wreg[(kq << 2) + 2] = v.z; wreg[(kq << 2) + 3] = v.w;
  }
#pragma unroll
  for (int kq = 0; kq < 16; ++kq) {
    float4 v = ld4(W_hh, g * 64 + (kq << 2), bf);
    wreg[32 + (kq << 2) + 0] = v.x; wreg[32 + (kq << 2) + 1] = v.y;
    wreg[32 + (kq << 2) + 2] = v.z; wreg[32 + (kq << 2) + 3] = v.w;
  }
  float bias = ldx(b_ih, g, bf) + ldx(b_hh, g, bf);

  xh[w][32 + lane] = 0.f;
  float c = 0.f;

  for (int t = 0; t < BB; ++t) {
    // stage hist for 4 nodes: col r = ti*8+f -> hist[((t*8+f)*NN+n)*5+ti]
    if (tid < 160) {
      int nd = tid / 40, r = tid % 40;
      int ti = r >> 3, f = r & 7;
      xstage[nd][r] = ldx(hist, ((t * FH + f) * NN + n0 + nd) * TIN + ti, bf);
    }
    __syncthreads();
    // x = elu(W1 @ xstage + b1): threads 0..127, nd = tid>>5, k = tid&31
    if (tid < 128) {
      int nd = tid >> 5, k = tid & 31;
      float acc = b1s[k];
#pragma unroll
      for (int j = 0; j < 40; ++j) acc += W1s[k][j] * xstage[nd][j];
      xh[nd][k] = (acc > 0.f) ? acc : expm1f(acc);
    }
    __syncthreads();
    float acc[4] = {bias, bias, bias, bias};
    const float4* xq0 = (const float4*)xh[0];
    const float4* xq1 = (const float4*)xh[1];
    const float4* xq2 = (const float4*)xh[2];
    const float4* xq3 = (const float4*)xh[3];
#pragma unroll
    for (int kq = 0; kq < 24; ++kq) {
      float w0 = wreg[(kq << 2) + 0], w1 = wreg[(kq << 2) + 1];
      float w2 = wreg[(kq << 2) + 2], w3 = wreg[(kq << 2) + 3];
      float4 v0 = xq0[kq], v1 = xq1[kq], v2 = xq2[kq], v3 = xq3[kq];
      acc[0] += w0 * v0.x + w1 * v0.y + w2 * v0.z + w3 * v0.w;
      acc[1] += w0 * v1.x + w1 * v1.y + w2 * v1.z + w3 * v1.w;
      acc[2] += w0 * v2.x + w1 * v2.y + w2 * v2.z + w3 * v2.w;
      acc[3] += w0 * v3.x + w1 * v3.y + w2 * v3.z + w3 * v3.w;
    }
#pragma unroll
    for (int nd = 0; nd < 4; ++nd) gbuf[nd][g] = acc[nd];
    __syncthreads();
    float gi = gbuf[w][lane];
    float gf = gbuf[w][64 + lane];
    float gg = gbuf[w][128 + lane];
    float go = gbuf[w][192 + lane];
    c = sigf(gf) * c + sigf(gi) * tanhf(gg);
    float h = sigf(go) * tanhf(c);
    xh[w][32 + lane] = h;
    hs[((t * NN + node_w) * H2) + lane] = h;
    __syncthreads();
  }
}

// ---------------------------------------------------------------- gatprep
__global__ __launch_bounds__(256) void k_gatprep(
    const float* __restrict__ hs, cvp Wg, cvp a_src, cvp a_dst,
    __hip_bfloat16* __restrict__ WhFr, float* __restrict__ sv,
    float* __restrict__ dv, const int* __restrict__ flagp) {
  __shared__ float wg[H2 * H2];
  __shared__ float tile[32][H2 + 1];
  int bf = *flagp;
  int tid = threadIdx.x;
  for (int i = tid; i < H2 * H2; i += 256) wg[i] = ldx(Wg, i, bf);
  __syncthreads();
  int wave = tid >> 6, lane = tid & 63;
  int b = blockIdx.x >> 6;
  int jt = blockIdx.x & 63;
  int j0 = jt << 5;
  float as = ldx(a_src, lane, bf);
  float ad = ldx(a_dst, lane, bf);
#pragma unroll
  for (int rr = 0; rr < 8; ++rr) {
    int jl = (wave << 3) + rr;
    int row = b * NN + j0 + jl;
    float hreg = hs[row * H2 + lane];
    float acc = 0.f;
#pragma unroll
    for (int k = 0; k < H2; ++k)
      acc += __shfl(hreg, k, 64) * wg[(k << 6) + lane];
    tile[jl][lane] = acc;
    float s = acc * as, d = acc * ad;
#pragma unroll
    for (int off = 32; off > 0; off >>= 1) {
      s += __shfl_xor(s, off, 64);
      d += __shfl_xor(d, off, 64);
    }
    if (lane == 0) { sv[row] = s; dv[row] = d; }
  }
  __syncthreads();
  int nt = tid >> 6, l = tid & 63;
  int q = l >> 4, m = l & 15;
  float v[8];
#pragma unroll
  for (int jj = 0; jj < 8; ++jj)
    v[jj] = tile[(q << 3) + jj][(nt << 4) + m];
  short8 fr;
#pragma unroll
  for (int p = 0; p < 4; ++p)
    ((__hip_bfloat162*)&fr)[p] =
        __float22bfloat162_rn(make_float2(v[2 * p], v[2 * p + 1]));
  size_t off = ((size_t)(b * 64 + jt) * 4 + nt) * 64 + l;
  ((short8*)WhFr)[off] = fr;
}

// ---------------------------------------------------------------- GAT
// Block = 4 waves, one 16-row i-tile. Prologue: adj rows -> LDS bitmasks
// (ballot, coalesced stream) + dv row -> LDS. Compute: wave w covers K-steps
// [w*16,(w+1)*16); per step only LDS + L2 b-frag loads; 5th MFMA vs an
// all-ones B-fragment accumulates softmax row-sums.
__global__ __launch_bounds__(256, 4) void k_gat(
    const int* __restrict__ adj, const __hip_bfloat16* __restrict__ WhFr,
    const float* __restrict__ sv, const float* __restrict__ dv,
    void* __restrict__ out, const int* __restrict__ flagp) {
  __shared__ __align__(16) float dv_s[NN];      // 8 KB
  __shared__ unsigned int msk[16 * 65];         // bank-padded masks
  __shared__ floatx4 abuf[3][5][64];            // 15 KB partials
  int bf = *flagp;
  int tid = threadIdx.x;
  int w = tid >> 6, lane = tid & 63;
  int b = blockIdx.x >> 7;
  int i0 = (blockIdx.x & 127) << 4;
  int q = lane >> 4, m = lane & 15;

  for (int j = tid; j < NN; j += 256) dv_s[j] = dv[b * NN + j];
  const int* adjb = adj + ((size_t)(b * 2 + 1) * NN + i0) * NN;
#pragma unroll
  for (int rr = 0; rr < 4; ++rr) {
    int row = (w << 2) + rr;
    const int* ar = adjb + (size_t)row * NN;
#pragma unroll 8
    for (int it = 0; it < 32; ++it) {
      int v = ar[(it << 6) + lane];
      unsigned long long bal = __ballot(v != 0);
      if (lane == 0) {
        msk[row * 65 + (it << 1)] = (unsigned)bal;
        msk[row * 65 + (it << 1) + 1] = (unsigned)(bal >> 32);
      }
    }
  }
  float sva = sv[b * NN + i0 + m];
  __syncthreads();

  short8 ones;
#pragma unroll
  for (int p = 0; p < 8; ++p) ones[p] = (short)0x3F80;

  const short8* base = ((const short8*)WhFr) + (size_t)b * 16384 + lane;
  int ksb = w << 4, kse = ksb + 16;
  floatx4 acc0 = {0.f, 0.f, 0.f, 0.f};
  floatx4 acc1 = acc0, acc2 = acc0, acc3 = acc0, accS = acc0;

  short8 cb0 = base[(size_t)ksb * 256];
  short8 cb1 = base[(size_t)ksb * 256 + 64];
  short8 cb2 = base[(size_t)ksb * 256 + 128];
  short8 cb3 = base[(size_t)ksb * 256 + 192];
  for (int ks = ksb; ks < kse; ++ks) {
    short8 b0 = cb0, b1 = cb1, b2 = cb2, b3 = cb3;
    int ksn = (ks + 1 < kse) ? ks + 1 : ks;
    cb0 = base[(size_t)ksn * 256];
    cb1 = base[(size_t)ksn * 256 + 64];
    cb2 = base[(size_t)ksn * 256 + 128];
    cb3 = base[(size_t)ksn * 256 + 192];
    unsigned mword = msk[m * 65 + ks];
    float4 d0 = *(const float4*)&dv_s[(ks << 5) + (q << 3)];
    float4 d1 = *(const float4*)&dv_s[(ks << 5) + (q << 3) + 4];
    float dd[8] = {d0.x, d0.y, d0.z, d0.w, d1.x, d1.y, d1.z, d1.w};
    float pv[8];
#pragma unroll
    for (int jj = 0; jj < 8; ++jj) {
      float t = sva + dd[jj];
      float e = __expf(fmaxf(t, 0.2f * t));
      pv[jj] = ((mword >> ((q << 3) + jj)) & 1u) ? e : 0.f;
    }
    short8 afr;
#pragma unroll
    for (int p2 = 0; p2 < 4; ++p2)
      ((__hip_bfloat162*)&afr)[p2] =
          __float22bfloat162_rn(make_float2(pv[2 * p2], pv[2 * p2 + 1]));
    acc0 = __builtin_amdgcn_mfma_f32_16x16x32_bf16(afr, b0, acc0, 0, 0, 0);
    acc1 = __builtin_amdgcn_mfma_f32_16x16x32_bf16(afr, b1, acc1, 0, 0, 0);
    acc2 = __builtin_amdgcn_mfma_f32_16x16x32_bf16(afr, b2, acc2, 0, 0, 0);
    acc3 = __builtin_amdgcn_mfma_f32_16x16x32_bf16(afr, b3, acc3, 0, 0, 0);
    accS = __builtin_amdgcn_mfma_f32_16x16x32_bf16(afr, ones, accS, 0, 0, 0);
  }
  if (w > 0) {
    abuf[w - 1][0][lane] = acc0;
    abuf[w - 1][1][lane] = acc1;
    abuf[w - 1][2][lane] = acc2;
    abuf[w - 1][3][lane] = acc3;
    abuf[w - 1][4][lane] = accS;
  }
  __syncthreads();
  if (w != 0) return;
#pragma unroll
  for (int ww = 0; ww < 3; ++ww) {
    acc0 += abuf[ww][0][lane];
    acc1 += abuf[ww][1][lane];
    acc2 += abuf[ww][2][lane];
    acc3 += abuf[ww][3][lane];
    accS += abuf[ww][4][lane];
  }
  floatx4 accs[4] = {acc0, acc1, acc2, acc3};
  float inv[4];
#pragma unroll
  for (int r = 0; r < 4; ++r) inv[r] = 1.f / accS[r];
  if (bf) {
    __hip_bfloat16* o = (__hip_bfloat16*)out;
#pragma unroll
    for (int nt = 0; nt < 4; ++nt)
#pragma unroll
      for (int r = 0; r < 4; ++r) {
        float v = accs[nt][r] * inv[r];
        v = (v > 0.f) ? v : expm1f(v);
        int row = i0 + (q << 2) + r;
        o[((size_t)b * NN + row) * H2 + (nt << 4) + m] = __float2bfloat16(v);
      }
  } else {
    float* o = (float*)out;
#pragma unroll
    for (int nt = 0; nt < 4; ++nt)
#pragma unroll
      for (int r = 0; r < 4; ++r) {
        float v = accs[nt][r] * inv[r];
        v = (v > 0.f) ? v : expm1f(v);
        int row = i0 + (q << 2) + r;
        o[((size_t)b * NN + row) * H2 + (nt << 4) + m] = v;
      }
  }
}

// ---------------------------------------------------------------- launch
extern "C" void kernel_launch(void* const* d_in, const int* in_sizes, int n_in,
                              void* d_out, int out_size, void* d_ws, size_t ws_size,
                              hipStream_t stream) {
  (void)in_sizes; (void)n_in; (void)out_size; (void)ws_size;
  cvp hist  = d_in[0];
  const int* adj = (const int*)d_in[1];
  cvp W1    = d_in[2];
  cvp b1    = d_in[3];
  cvp W_ih  = d_in[4];
  cvp W_hh  = d_in[5];
  cvp b_ih  = d_in[6];
  cvp b_hh  = d_in[7];
  cvp Wg    = d_in[8];
  cvp a_src = d_in[9];
  cvp a_dst = d_in[10];

  float* ws  = (float*)d_ws;
  float* hs  = ws;                                   // B*N*H2 = 1048576 f
  __hip_bfloat16* WhFr = (__hip_bfloat16*)(hs + BB * NN * H2);  // 2 MB
  float* sv  = hs + BB * NN * H2 + 524288;
  float* dv  = sv + BB * NN;
  int* flag  = (int*)(dv + BB * NN);

  k_detect<<<1, 256, 0, stream>>>((const unsigned int*)W_ih, flag);
  k_lstm<<<512, 256, 0, stream>>>(hist, W1, b1, W_ih, W_hh, b_ih, b_hh, hs, flag);
  k_gatprep<<<512, 256, 0, stream>>>(hs, Wg, a_src, a_dst, WhFr, sv, dv, flag);
  k_gat<<<1024, 256, 0, stream>>>(adj, WhFr, sv, dv, d_out, flag);
}

// Round 5
// 467.021 us; speedup vs baseline: 1.0003x; 1.0003x over previous
//
#include <hip/hip_runtime.h>
#include <hip/hip_bf16.h>
#include <math.h>

#define BB 8
#define FH 8
#define NN 2048
#define TIN 5
#define H1 32
#define H2 64

typedef const void* cvp;
typedef __attribute__((ext_vector_type(8))) short short8;
typedef __attribute__((ext_vector_type(4))) float floatx4;

__device__ __forceinline__ float ldx(cvp p, int i, int bf) {
  if (bf) return __bfloat162float(((const __hip_bfloat16*)p)[i]);
  return ((const float*)p)[i];
}

__device__ __forceinline__ float4 ld4(cvp p, int i, int bf) {
  if (bf) {
    const __hip_bfloat162* q = (const __hip_bfloat162*)p;
    float2 a = __bfloat1622float2(q[(i >> 1)]);
    float2 b = __bfloat1622float2(q[(i >> 1) + 1]);
    return make_float4(a.x, a.y, b.x, b.y);
  }
  return ((const float4*)p)[i >> 2];
}

__device__ __forceinline__ float sigf(float x) {
  return 1.f / (1.f + __expf(-x));
}

// ---------------------------------------------------------------- detector
__global__ void k_detect(const unsigned int* __restrict__ w, int* __restrict__ flag) {
  __shared__ int cnt;
  if (threadIdx.x == 0) cnt = 0;
  __syncthreads();
  int local = 0;
  for (int i = threadIdx.x; i < 1024; i += 256) {
    unsigned e = (w[i] >> 7) & 0xFFu;
    local += (e >= 100u && e <= 150u) ? 1 : 0;
  }
  atomicAdd(&cnt, local);
  __syncthreads();
  if (threadIdx.x == 0) *flag = (cnt > 700) ? 1 : 0;
}

// ---------------------------------------------------------------- LSTM (h1 fused)
__global__ __launch_bounds__(256, 2) void k_lstm(
    cvp hist, cvp W1, cvp b1, cvp W_ih, cvp W_hh, cvp b_ih, cvp b_hh,
    float* __restrict__ hs, const int* __restrict__ flagp) {
  __shared__ __align__(16) float xh[4][96];   // per node: x[0..31], h[32..95]
  __shared__ float gbuf[4][256];
  __shared__ float W1s[H1][41];               // bank-padded
  __shared__ float b1s[H1];
  __shared__ float xstage[4][40];
  int bf = *flagp;
  int tid = threadIdx.x;
  int w = tid >> 6, lane = tid & 63;
  int g = (w << 6) + lane;
  int n0 = blockIdx.x << 2;
  int node_w = n0 + w;

  for (int i = tid; i < H1 * 40; i += 256) W1s[i / 40][i % 40] = ldx(W1, i, bf);
  if (tid < H1) b1s[tid] = ldx(b1, tid, bf);

  float wreg[96];
#pragma unroll
  for (int kq = 0; kq < 8; ++kq) {
    float4 v = ld4(W_ih, g * 32 + (kq << 2), bf);
    wreg[(kq << 2) + 0] = v.x; wreg[(kq << 2) + 1] = v.y;
    wreg[(kq << 2) + 2] = v.z; wreg[(kq << 2) + 3] = v.w;
  }
#pragma unroll
  for (int kq = 0; kq < 16; ++kq) {
    float4 v = ld4(W_hh, g * 64 + (kq << 2), bf);
    wreg[32 + (kq << 2) + 0] = v.x; wreg[32 + (kq << 2) + 1] = v.y;
    wreg[32 + (kq << 2) + 2] = v.z; wreg[32 + (kq << 2) + 3] = v.w;
  }
  float bias = ldx(b_ih, g, bf) + ldx(b_hh, g, bf);

  xh[w][32 + lane] = 0.f;
  float c = 0.f;

  for (int t = 0; t < BB; ++t) {
    if (tid < 160) {
      int nd = tid / 40, r = tid % 40;
      int ti = r >> 3, f = r & 7;
      xstage[nd][r] = ldx(hist, ((t * FH + f) * NN + n0 + nd) * TIN + ti, bf);
    }
    __syncthreads();
    if (tid < 128) {
      int nd = tid >> 5, k = tid & 31;
      float acc = b1s[k];
#pragma unroll
      for (int j = 0; j < 40; ++j) acc += W1s[k][j] * xstage[nd][j];
      xh[nd][k] = (acc > 0.f) ? acc : expm1f(acc);
    }
    __syncthreads();
    float acc[4] = {bias, bias, bias, bias};
    const float4* xq0 = (const float4*)xh[0];
    const float4* xq1 = (const float4*)xh[1];
    const float4* xq2 = (const float4*)xh[2];
    const float4* xq3 = (const float4*)xh[3];
#pragma unroll
    for (int kq = 0; kq < 24; ++kq) {
      float w0 = wreg[(kq << 2) + 0], w1 = wreg[(kq << 2) + 1];
      float w2 = wreg[(kq << 2) + 2], w3 = wreg[(kq << 2) + 3];
      float4 v0 = xq0[kq], v1 = xq1[kq], v2 = xq2[kq], v3 = xq3[kq];
      acc[0] += w0 * v0.x + w1 * v0.y + w2 * v0.z + w3 * v0.w;
      acc[1] += w0 * v1.x + w1 * v1.y + w2 * v1.z + w3 * v1.w;
      acc[2] += w0 * v2.x + w1 * v2.y + w2 * v2.z + w3 * v2.w;
      acc[3] += w0 * v3.x + w1 * v3.y + w2 * v3.z + w3 * v3.w;
    }
#pragma unroll
    for (int nd = 0; nd < 4; ++nd) gbuf[nd][g] = acc[nd];
    __syncthreads();
    float gi = gbuf[w][lane];
    float gf = gbuf[w][64 + lane];
    float gg = gbuf[w][128 + lane];
    float go = gbuf[w][192 + lane];
    c = sigf(gf) * c + sigf(gi) * tanhf(gg);
    float h = sigf(go) * tanhf(c);
    xh[w][32 + lane] = h;
    hs[((t * NN + node_w) * H2) + lane] = h;
    __syncthreads();
  }
}

// ---------------------------------------------------------------- gatprep
__global__ __launch_bounds__(256) void k_gatprep(
    const float* __restrict__ hs, cvp Wg, cvp a_src, cvp a_dst,
    __hip_bfloat16* __restrict__ WhFr, float* __restrict__ sv,
    float* __restrict__ dv, const int* __restrict__ flagp) {
  __shared__ float wg[H2 * H2];
  __shared__ float tile[32][H2 + 1];
  int bf = *flagp;
  int tid = threadIdx.x;
  for (int i = tid; i < H2 * H2; i += 256) wg[i] = ldx(Wg, i, bf);
  __syncthreads();
  int wave = tid >> 6, lane = tid & 63;
  int b = blockIdx.x >> 6;
  int jt = blockIdx.x & 63;
  int j0 = jt << 5;
  float as = ldx(a_src, lane, bf);
  float ad = ldx(a_dst, lane, bf);
#pragma unroll
  for (int rr = 0; rr < 8; ++rr) {
    int jl = (wave << 3) + rr;
    int row = b * NN + j0 + jl;
    float hreg = hs[row * H2 + lane];
    float acc = 0.f;
#pragma unroll
    for (int k = 0; k < H2; ++k)
      acc += __shfl(hreg, k, 64) * wg[(k << 6) + lane];
    tile[jl][lane] = acc;
    float s = acc * as, d = acc * ad;
#pragma unroll
    for (int off = 32; off > 0; off >>= 1) {
      s += __shfl_xor(s, off, 64);
      d += __shfl_xor(d, off, 64);
    }
    if (lane == 0) { sv[row] = s; dv[row] = d; }
  }
  __syncthreads();
  int nt = tid >> 6, l = tid & 63;
  int q = l >> 4, m = l & 15;
  float v[8];
#pragma unroll
  for (int jj = 0; jj < 8; ++jj)
    v[jj] = tile[(q << 3) + jj][(nt << 4) + m];
  short8 fr;
#pragma unroll
  for (int p = 0; p < 4; ++p)
    ((__hip_bfloat162*)&fr)[p] =
        __float22bfloat162_rn(make_float2(v[2 * p], v[2 * p + 1]));
  size_t off = ((size_t)(b * 64 + jt) * 4 + nt) * 64 + l;
  ((short8*)WhFr)[off] = fr;
}

// ---------------------------------------------------------------- GAT
// Block = 4 waves, one 16-row i-tile. Prologue: adj -> LDS bitmasks (ballot),
// dv row -> LDS. Compute: wave w covers K-steps [w*16,(w+1)*16); per step
// only LDS + L2 b-frag loads (no software prefetch -- TLP hides L2 latency;
// prefetch regs at launch_bounds(256,4) caused spills in r4). 5th MFMA vs
// all-ones B accumulates softmax row-sums.
__global__ __launch_bounds__(256, 3) void k_gat(
    const int* __restrict__ adj, const __hip_bfloat16* __restrict__ WhFr,
    const float* __restrict__ sv, const float* __restrict__ dv,
    void* __restrict__ out, const int* __restrict__ flagp) {
  __shared__ __align__(16) float dv_s[NN];      // 8 KB
  __shared__ unsigned int msk[16 * 65];         // 4.2 KB, bank-padded
  __shared__ floatx4 abuf[3][5][64];            // 15 KB partials
  int bf = *flagp;
  int tid = threadIdx.x;
  int w = tid >> 6, lane = tid & 63;
  int b = blockIdx.x >> 7;
  int i0 = (blockIdx.x & 127) << 4;
  int q = lane >> 4, m = lane & 15;

  for (int j = tid; j < NN; j += 256) dv_s[j] = dv[b * NN + j];
  const int* adjb = adj + ((size_t)(b * 2 + 1) * NN + i0) * NN;
#pragma unroll
  for (int rr = 0; rr < 4; ++rr) {
    int row = (w << 2) + rr;
    const int* ar = adjb + (size_t)row * NN;
#pragma unroll 8
    for (int it = 0; it < 32; ++it) {
      int v = ar[(it << 6) + lane];
      unsigned long long bal = __ballot(v != 0);
      if (lane == 0) {
        msk[row * 65 + (it << 1)] = (unsigned)bal;
        msk[row * 65 + (it << 1) + 1] = (unsigned)(bal >> 32);
      }
    }
  }
  float sva = sv[b * NN + i0 + m];
  __syncthreads();

  short8 ones;
#pragma unroll
  for (int p = 0; p < 8; ++p) ones[p] = (short)0x3F80;

  const short8* base = ((const short8*)WhFr) + (size_t)b * 16384 + lane;
  int ksb = w << 4, kse = ksb + 16;
  floatx4 acc0 = {0.f, 0.f, 0.f, 0.f};
  floatx4 acc1 = acc0, acc2 = acc0, acc3 = acc0, accS = acc0;

  for (int ks = ksb; ks < kse; ++ks) {
    const short8* b_ks = base + (size_t)ks * 256;
    short8 b0 = b_ks[0];
    short8 b1 = b_ks[64];
    short8 b2 = b_ks[128];
    short8 b3 = b_ks[192];
    unsigned mword = msk[m * 65 + ks];
    float4 d0 = *(const float4*)&dv_s[(ks << 5) + (q << 3)];
    float4 d1 = *(const float4*)&dv_s[(ks << 5) + (q << 3) + 4];
    float dd[8] = {d0.x, d0.y, d0.z, d0.w, d1.x, d1.y, d1.z, d1.w};
    float pv[8];
#pragma unroll
    for (int jj = 0; jj < 8; ++jj) {
      float t = sva + dd[jj];
      float e = __expf(fmaxf(t, 0.2f * t));
      pv[jj] = ((mword >> ((q << 3) + jj)) & 1u) ? e : 0.f;
    }
    short8 afr;
#pragma unroll
    for (int p2 = 0; p2 < 4; ++p2)
      ((__hip_bfloat162*)&afr)[p2] =
          __float22bfloat162_rn(make_float2(pv[2 * p2], pv[2 * p2 + 1]));
    acc0 = __builtin_amdgcn_mfma_f32_16x16x32_bf16(afr, b0, acc0, 0, 0, 0);
    acc1 = __builtin_amdgcn_mfma_f32_16x16x32_bf16(afr, b1, acc1, 0, 0, 0);
    acc2 = __builtin_amdgcn_mfma_f32_16x16x32_bf16(afr, b2, acc2, 0, 0, 0);
    acc3 = __builtin_amdgcn_mfma_f32_16x16x32_bf16(afr, b3, acc3, 0, 0, 0);
    accS = __builtin_amdgcn_mfma_f32_16x16x32_bf16(afr, ones, accS, 0, 0, 0);
  }
  if (w > 0) {
    abuf[w - 1][0][lane] = acc0;
    abuf[w - 1][1][lane] = acc1;
    abuf[w - 1][2][lane] = acc2;
    abuf[w - 1][3][lane] = acc3;
    abuf[w - 1][4][lane] = accS;
  }
  __syncthreads();
  if (w != 0) return;
#pragma unroll
  for (int ww = 0; ww < 3; ++ww) {
    acc0 += abuf[ww][0][lane];
    acc1 += abuf[ww][1][lane];
    acc2 += abuf[ww][2][lane];
    acc3 += abuf[ww][3][lane];
    accS += abuf[ww][4][lane];
  }
  floatx4 accs[4] = {acc0, acc1, acc2, acc3};
  float inv[4];
#pragma unroll
  for (int r = 0; r < 4; ++r) inv[r] = 1.f / accS[r];
  if (bf) {
    __hip_bfloat16* o = (__hip_bfloat16*)out;
#pragma unroll
    for (int nt = 0; nt < 4; ++nt)
#pragma unroll
      for (int r = 0; r < 4; ++r) {
        float v = accs[nt][r] * inv[r];
        v = (v > 0.f) ? v : expm1f(v);
        int row = i0 + (q << 2) + r;
        o[((size_t)b * NN + row) * H2 + (nt << 4) + m] = __float2bfloat16(v);
      }
  } else {
    float* o = (float*)out;
#pragma unroll
    for (int nt = 0; nt < 4; ++nt)
#pragma unroll
      for (int r = 0; r < 4; ++r) {
        float v = accs[nt][r] * inv[r];
        v = (v > 0.f) ? v : expm1f(v);
        int row = i0 + (q << 2) + r;
        o[((size_t)b * NN + row) * H2 + (nt << 4) + m] = v;
      }
  }
}

// ---------------------------------------------------------------- launch
extern "C" void kernel_launch(void* const* d_in, const int* in_sizes, int n_in,
                              void* d_out, int out_size, void* d_ws, size_t ws_size,
                              hipStream_t stream) {
  (void)in_sizes; (void)n_in; (void)out_size; (void)ws_size;
  cvp hist  = d_in[0];
  const int* adj = (const int*)d_in[1];
  cvp W1    = d_in[2];
  cvp b1    = d_in[3];
  cvp W_ih  = d_in[4];
  cvp W_hh  = d_in[5];
  cvp b_ih  = d_in[6];
  cvp b_hh  = d_in[7];
  cvp Wg    = d_in[8];
  cvp a_src = d_in[9];
  cvp a_dst = d_in[10];

  float* ws  = (float*)d_ws;
  float* hs  = ws;                                   // B*N*H2 = 1048576 f
  __hip_bfloat16* WhFr = (__hip_bfloat16*)(hs + BB * NN * H2);  // 2 MB
  float* sv  = hs + BB * NN * H2 + 524288;
  float* dv  = sv + BB * NN;
  int* flag  = (int*)(dv + BB * NN);

  k_detect<<<1, 256, 0, stream>>>((const unsigned int*)W_ih, flag);
  k_lstm<<<512, 256, 0, stream>>>(hist, W1, b1, W_ih, W_hh, b_ih, b_hh, hs, flag);
  k_gatprep<<<512, 256, 0, stream>>>(hs, Wg, a_src, a_dst, WhFr, sv, dv, flag);
  k_gat<<<1024, 256, 0, stream>>>(adj, WhFr, sv, dv, d_out, flag);
}

// Round 6
// 418.146 us; speedup vs baseline: 1.1172x; 1.1169x over previous
//
#include <hip/hip_runtime.h>
#include <hip/hip_bf16.h>
#include <math.h>

#define BB 8
#define FH 8
#define NN 2048
#define TIN 5
#define H1 32
#define H2 64

typedef const void* cvp;
typedef __attribute__((ext_vector_type(8))) short short8;
typedef __attribute__((ext_vector_type(4))) float floatx4;

__device__ __forceinline__ float ldx(cvp p, int i, int bf) {
  if (bf) return __bfloat162float(((const __hip_bfloat16*)p)[i]);
  return ((const float*)p)[i];
}

__device__ __forceinline__ float4 ld4(cvp p, int i, int bf) {
  if (bf) {
    const __hip_bfloat162* q = (const __hip_bfloat162*)p;
    float2 a = __bfloat1622float2(q[(i >> 1)]);
    float2 b = __bfloat1622float2(q[(i >> 1) + 1]);
    return make_float4(a.x, a.y, b.x, b.y);
  }
  return ((const float4*)p)[i >> 2];
}

__device__ __forceinline__ float sigf(float x) {
  return 1.f / (1.f + __expf(-x));
}

// Inline bf16-vs-fp32 detector: 64 word samples of W_ih. bf16 data -> low-16
// exponent field in [100,150] for ~all words; fp32 -> ~20%. Same statistic as
// the old k_detect (0.69 threshold), computed per-wave with zero LDS.
__device__ __forceinline__ int detect_bf(cvp wih) {
  unsigned word = ((const unsigned*)wih)[threadIdx.x & 63];
  unsigned e = (word >> 7) & 0xFFu;
  unsigned long long bal = __ballot(e >= 100u && e <= 150u);
  return __popcll(bal) > 44;
}

// ---------------------------------------------------------------- LSTM (h1 fused)
__global__ __launch_bounds__(256, 2) void k_lstm(
    cvp hist, cvp W1, cvp b1, cvp W_ih, cvp W_hh, cvp b_ih, cvp b_hh,
    float* __restrict__ hs) {
  __shared__ __align__(16) float xh[4][96];   // per node: x[0..31], h[32..95]
  __shared__ float gbuf[4][256];
  __shared__ float W1s[H1][41];               // bank-padded
  __shared__ float b1s[H1];
  __shared__ float xstage[4][40];
  int bf = detect_bf(W_ih);
  int tid = threadIdx.x;
  int w = tid >> 6, lane = tid & 63;
  int g = (w << 6) + lane;
  int n0 = blockIdx.x << 2;
  int node_w = n0 + w;

  for (int i = tid; i < H1 * 40; i += 256) W1s[i / 40][i % 40] = ldx(W1, i, bf);
  if (tid < H1) b1s[tid] = ldx(b1, tid, bf);

  float wreg[96];
#pragma unroll
  for (int kq = 0; kq < 8; ++kq) {
    float4 v = ld4(W_ih, g * 32 + (kq << 2), bf);
    wreg[(kq << 2) + 0] = v.x; wreg[(kq << 2) + 1] = v.y;
    wreg[(kq << 2) + 2] = v.z; wreg[(kq << 2) + 3] = v.w;
  }
#pragma unroll
  for (int kq = 0; kq < 16; ++kq) {
    float4 v = ld4(W_hh, g * 64 + (kq << 2), bf);
    wreg[32 + (kq << 2) + 0] = v.x; wreg[32 + (kq << 2) + 1] = v.y;
    wreg[32 + (kq << 2) + 2] = v.z; wreg[32 + (kq << 2) + 3] = v.w;
  }
  float bias = ldx(b_ih, g, bf) + ldx(b_hh, g, bf);

  xh[w][32 + lane] = 0.f;
  float c = 0.f;

  for (int t = 0; t < BB; ++t) {
    if (tid < 160) {
      int nd = tid / 40, r = tid % 40;
      int ti = r >> 3, f = r & 7;
      xstage[nd][r] = ldx(hist, ((t * FH + f) * NN + n0 + nd) * TIN + ti, bf);
    }
    __syncthreads();
    if (tid < 128) {
      int nd = tid >> 5, k = tid & 31;
      float acc = b1s[k];
#pragma unroll
      for (int j = 0; j < 40; ++j) acc += W1s[k][j] * xstage[nd][j];
      xh[nd][k] = (acc > 0.f) ? acc : expm1f(acc);
    }
    __syncthreads();
    float acc[4] = {bias, bias, bias, bias};
    const float4* xq0 = (const float4*)xh[0];
    const float4* xq1 = (const float4*)xh[1];
    const float4* xq2 = (const float4*)xh[2];
    const float4* xq3 = (const float4*)xh[3];
#pragma unroll
    for (int kq = 0; kq < 24; ++kq) {
      float w0 = wreg[(kq << 2) + 0], w1 = wreg[(kq << 2) + 1];
      float w2 = wreg[(kq << 2) + 2], w3 = wreg[(kq << 2) + 3];
      float4 v0 = xq0[kq], v1 = xq1[kq], v2 = xq2[kq], v3 = xq3[kq];
      acc[0] += w0 * v0.x + w1 * v0.y + w2 * v0.z + w3 * v0.w;
      acc[1] += w0 * v1.x + w1 * v1.y + w2 * v1.z + w3 * v1.w;
      acc[2] += w0 * v2.x + w1 * v2.y + w2 * v2.z + w3 * v2.w;
      acc[3] += w0 * v3.x + w1 * v3.y + w2 * v3.z + w3 * v3.w;
    }
#pragma unroll
    for (int nd = 0; nd < 4; ++nd) gbuf[nd][g] = acc[nd];
    __syncthreads();
    float gi = gbuf[w][lane];
    float gf = gbuf[w][64 + lane];
    float gg = gbuf[w][128 + lane];
    float go = gbuf[w][192 + lane];
    c = sigf(gf) * c + sigf(gi) * tanhf(gg);
    float h = sigf(go) * tanhf(c);
    xh[w][32 + lane] = h;
    hs[((t * NN + node_w) * H2) + lane] = h;
    __syncthreads();
  }
}

// ---------------------------------------------------------------- gatprep
__global__ __launch_bounds__(256) void k_gatprep(
    const float* __restrict__ hs, cvp Wg, cvp a_src, cvp a_dst, cvp W_ih,
    __hip_bfloat16* __restrict__ WhFr, float* __restrict__ sv,
    float* __restrict__ dv) {
  __shared__ float wg[H2 * H2];
  __shared__ float tile[32][H2 + 1];
  int bf = detect_bf(W_ih);
  int tid = threadIdx.x;
  for (int i = tid; i < H2 * H2; i += 256) wg[i] = ldx(Wg, i, bf);
  __syncthreads();
  int wave = tid >> 6, lane = tid & 63;
  int b = blockIdx.x >> 6;
  int jt = blockIdx.x & 63;
  int j0 = jt << 5;
  float as = ldx(a_src, lane, bf);
  float ad = ldx(a_dst, lane, bf);
#pragma unroll
  for (int rr = 0; rr < 8; ++rr) {
    int jl = (wave << 3) + rr;
    int row = b * NN + j0 + jl;
    float hreg = hs[row * H2 + lane];
    float acc = 0.f;
#pragma unroll
    for (int k = 0; k < H2; ++k)
      acc += __shfl(hreg, k, 64) * wg[(k << 6) + lane];
    tile[jl][lane] = acc;
    float s = acc * as, d = acc * ad;
#pragma unroll
    for (int off = 32; off > 0; off >>= 1) {
      s += __shfl_xor(s, off, 64);
      d += __shfl_xor(d, off, 64);
    }
    if (lane == 0) { sv[row] = s; dv[row] = d; }
  }
  __syncthreads();
  int nt = tid >> 6, l = tid & 63;
  int q = l >> 4, m = l & 15;
  float v[8];
#pragma unroll
  for (int jj = 0; jj < 8; ++jj)
    v[jj] = tile[(q << 3) + jj][(nt << 4) + m];
  short8 fr;
#pragma unroll
  for (int p = 0; p < 4; ++p)
    ((__hip_bfloat162*)&fr)[p] =
        __float22bfloat162_rn(make_float2(v[2 * p], v[2 * p + 1]));
  size_t off = ((size_t)(b * 64 + jt) * 4 + nt) * 64 + l;
  ((short8*)WhFr)[off] = fr;
}

// ---------------------------------------------------------------- GAT
// Block = 4 waves, one 16-row i-tile.
// Phase 1: DENSE adj stream -- 128 independent int4 wave-insts per block
// (1 KB contiguous each), nibble-pack -> LDS atomicOr bitmasks. 16 loads in
// flight per wave (unroll 16) x 16 waves/CU saturates HBM (vs r4/r5's 256 B
// dword+ballot batches at ~1 TB/s).
// Phase 2: wave w covers K-steps [w*16,(w+1)*16); LDS masks + LDS dv + L2
// WhFr b-frags + 5 MFMAs (5th vs all-ones B = softmax row-sums).
__global__ __launch_bounds__(256, 4) void k_gat(
    const int* __restrict__ adj, const __hip_bfloat16* __restrict__ WhFr,
    const float* __restrict__ sv, const float* __restrict__ dv,
    void* __restrict__ out, cvp W_ih) {
  __shared__ __align__(16) float dv_s[NN];      // 8 KB
  __shared__ unsigned int msk[16 * 65];         // 4.16 KB, bank-padded
  __shared__ floatx4 abuf[3][5][64];            // 15 KB partials
  int bf = detect_bf(W_ih);
  int tid = threadIdx.x;
  int w = tid >> 6, lane = tid & 63;
  int b = blockIdx.x >> 7;
  int i0 = (blockIdx.x & 127) << 4;
  int q = lane >> 4, m = lane & 15;

  for (int j = tid; j < 16 * 65; j += 256) msk[j] = 0u;
  for (int j = tid; j < NN; j += 256) dv_s[j] = dv[b * NN + j];
  float sva = sv[b * NN + i0 + m];
  __syncthreads();

  // Phase 1: dense stream. inst g = row*8 + seg; wave w handles g in [w*32, w*32+32)
  const int4* adj4 = (const int4*)(adj + ((size_t)(b * 2 + 1) * NN + i0) * NN);
#pragma unroll 16
  for (int gi = 0; gi < 32; ++gi) {
    int g = (w << 5) + gi;
    int row = g >> 3, seg = g & 7;
    int4 v = adj4[(size_t)row * 512 + (seg << 6) + lane];
    unsigned nib = (v.x != 0 ? 1u : 0u) | (v.y != 0 ? 2u : 0u) |
                   (v.z != 0 ? 4u : 0u) | (v.w != 0 ? 8u : 0u);
    atomicOr(&msk[row * 65 + (seg << 3) + (lane >> 3)], nib << ((lane & 7) << 2));
  }
  __syncthreads();

  short8 ones;
#pragma unroll
  for (int p = 0; p < 8; ++p) ones[p] = (short)0x3F80;

  const short8* base = ((const short8*)WhFr) + (size_t)b * 16384 + lane;
  int ksb = w << 4, kse = ksb + 16;
  floatx4 acc0 = {0.f, 0.f, 0.f, 0.f};
  floatx4 acc1 = acc0, acc2 = acc0, acc3 = acc0, accS = acc0;

  for (int ks = ksb; ks < kse; ++ks) {
    const short8* b_ks = base + (size_t)ks * 256;
    short8 b0 = b_ks[0];
    short8 b1 = b_ks[64];
    short8 b2 = b_ks[128];
    short8 b3 = b_ks[192];
    unsigned mword = msk[m * 65 + ks];
    float4 d0 = *(const float4*)&dv_s[(ks << 5) + (q << 3)];
    float4 d1 = *(const float4*)&dv_s[(ks << 5) + (q << 3) + 4];
    float dd[8] = {d0.x, d0.y, d0.z, d0.w, d1.x, d1.y, d1.z, d1.w};
    float pv[8];
#pragma unroll
    for (int jj = 0; jj < 8; ++jj) {
      float t = sva + dd[jj];
      float e = __expf(fmaxf(t, 0.2f * t));
      pv[jj] = ((mword >> ((q << 3) + jj)) & 1u) ? e : 0.f;
    }
    short8 afr;
#pragma unroll
    for (int p2 = 0; p2 < 4; ++p2)
      ((__hip_bfloat162*)&afr)[p2] =
          __float22bfloat162_rn(make_float2(pv[2 * p2], pv[2 * p2 + 1]));
    acc0 = __builtin_amdgcn_mfma_f32_16x16x32_bf16(afr, b0, acc0, 0, 0, 0);
    acc1 = __builtin_amdgcn_mfma_f32_16x16x32_bf16(afr, b1, acc1, 0, 0, 0);
    acc2 = __builtin_amdgcn_mfma_f32_16x16x32_bf16(afr, b2, acc2, 0, 0, 0);
    acc3 = __builtin_amdgcn_mfma_f32_16x16x32_bf16(afr, b3, acc3, 0, 0, 0);
    accS = __builtin_amdgcn_mfma_f32_16x16x32_bf16(afr, ones, accS, 0, 0, 0);
  }
  if (w > 0) {
    abuf[w - 1][0][lane] = acc0;
    abuf[w - 1][1][lane] = acc1;
    abuf[w - 1][2][lane] = acc2;
    abuf[w - 1][3][lane] = acc3;
    abuf[w - 1][4][lane] = accS;
  }
  __syncthreads();
  if (w != 0) return;
#pragma unroll
  for (int ww = 0; ww < 3; ++ww) {
    acc0 += abuf[ww][0][lane];
    acc1 += abuf[ww][1][lane];
    acc2 += abuf[ww][2][lane];
    acc3 += abuf[ww][3][lane];
    accS += abuf[ww][4][lane];
  }
  floatx4 accs[4] = {acc0, acc1, acc2, acc3};
  float inv[4];
#pragma unroll
  for (int r = 0; r < 4; ++r) inv[r] = 1.f / accS[r];
  if (bf) {
    __hip_bfloat16* o = (__hip_bfloat16*)out;
#pragma unroll
    for (int nt = 0; nt < 4; ++nt)
#pragma unroll
      for (int r = 0; r < 4; ++r) {
        float v = accs[nt][r] * inv[r];
        v = (v > 0.f) ? v : expm1f(v);
        int row = i0 + (q << 2) + r;
        o[((size_t)b * NN + row) * H2 + (nt << 4) + m] = __float2bfloat16(v);
      }
  } else {
    float* o = (float*)out;
#pragma unroll
    for (int nt = 0; nt < 4; ++nt)
#pragma unroll
      for (int r = 0; r < 4; ++r) {
        float v = accs[nt][r] * inv[r];
        v = (v > 0.f) ? v : expm1f(v);
        int row = i0 + (q << 2) + r;
        o[((size_t)b * NN + row) * H2 + (nt << 4) + m] = v;
      }
  }
}

// ---------------------------------------------------------------- launch
extern "C" void kernel_launch(void* const* d_in, const int* in_sizes, int n_in,
                              void* d_out, int out_size, void* d_ws, size_t ws_size,
                              hipStream_t stream) {
  (void)in_sizes; (void)n_in; (void)out_size; (void)ws_size;
  cvp hist  = d_in[0];
  const int* adj = (const int*)d_in[1];
  cvp W1    = d_in[2];
  cvp b1    = d_in[3];
  cvp W_ih  = d_in[4];
  cvp W_hh  = d_in[5];
  cvp b_ih  = d_in[6];
  cvp b_hh  = d_in[7];
  cvp Wg    = d_in[8];
  cvp a_src = d_in[9];
  cvp a_dst = d_in[10];

  float* ws  = (float*)d_ws;
  float* hs  = ws;                                   // B*N*H2 = 1048576 f
  __hip_bfloat16* WhFr = (__hip_bfloat16*)(hs + BB * NN * H2);  // 2 MB
  float* sv  = hs + BB * NN * H2 + 524288;
  float* dv  = sv + BB * NN;

  k_lstm<<<512, 256, 0, stream>>>(hist, W1, b1, W_ih, W_hh, b_ih, b_hh, hs);
  k_gatprep<<<512, 256, 0, stream>>>(hs, Wg, a_src, a_dst, W_ih, WhFr, sv, dv);
  k_gat<<<1024, 256, 0, stream>>>(adj, WhFr, sv, dv, d_out, W_ih);
}